// Round 8
// baseline (199.524 us; speedup 1.0000x reference)
//
#include <hip/hip_runtime.h>

#define N_FEAT 1024
#define N_LAYER 4
#define ROWS_PER_WAVE 4   // 2 iterations x 2 rows
#define PAIR 2

// Algebra: xi = A_i*x0 + C_i, C_i = sum_{j<i} b_j (row-independent).
//   p_i = <x0,w_i>, e_i = <C_i,w_i>; A_{i+1} = A_i*(1+p_i) + e_i;
//   out = A_4*x0 + csum.
//
// R7 retry without the spill-inducer. R7's counters showed the (256,4)
// 128-VGPR cap + explicit next-pair prefetch (xv+nxt = 64 regs of data)
// spilled ~96 floats/thread to scratch (+96MB writes, +32MB reads) -> test
// void. This version deletes the ILP prefetch and relies on TLP: 16
// waves/CU (4 blocks/CU, grid 1024 = 4x256 exactly, all resident at t=0)
// each issuing 8 independent float4 loads per pair-iteration. Live state
// ~70 VGPR -> no spill at the 128 cap.
//  - w (16KB) + csum (4KB) in LDS, written redundantly by every wave
//    (identical bits -> benign race, wave reads own writes, zero barriers).
//  - per-byte overhead identical to R0/R4/R5 (48 shuffles per 8KB rows).
// Validity check in counters: WRITE ~= 65MB, FETCH ~= 64-70MB (no scratch).
__global__ __launch_bounds__(256, 4) void crossnet_kernel(
    const float* __restrict__ x,
    const float* __restrict__ weight_w,
    const float* __restrict__ weight_b,
    float* __restrict__ out,
    int n_rows) {
  const int wave = threadIdx.x >> 6;   // 0..3
  const int lane = threadIdx.x & 63;

  __shared__ float4 w_lds[N_LAYER * 256];  // [layer][col] 16 KB
  __shared__ float4 csum_lds[256];         // 4 KB

  // ---- preamble (per wave, redundant, barrier-free): w->LDS, csum->LDS, e ----
  float e[N_LAYER] = {0.f, 0.f, 0.f, 0.f};
#pragma unroll
  for (int c = 0; c < 4; ++c) {
    const int col = c * 64 + lane;
    float4 wv[N_LAYER];
#pragma unroll
    for (int i = 0; i < N_LAYER; ++i) {
      wv[i] = ((const float4*)(weight_w + i * N_FEAT))[col];
      w_lds[i * 256 + col] = wv[i];
    }
    float4 cum = make_float4(0.f, 0.f, 0.f, 0.f);
#pragma unroll
    for (int i = 0; i < N_LAYER; ++i) {
      if (i > 0)
        e[i] += cum.x * wv[i].x + cum.y * wv[i].y +
                cum.z * wv[i].z + cum.w * wv[i].w;
      const float4 b = ((const float4*)(weight_b + i * N_FEAT))[col];
      cum.x += b.x; cum.y += b.y; cum.z += b.z; cum.w += b.w;
    }
    csum_lds[col] = cum;
  }
#pragma unroll
  for (int off = 32; off > 0; off >>= 1)
#pragma unroll
    for (int i = 1; i < N_LAYER; ++i) e[i] += __shfl_xor(e[i], off, 64);

  // ---- row range for this wave: 4 contiguous rows ----
  const int g = blockIdx.x * 4 + wave;
  const int row_base = g * ROWS_PER_WAVE;
  if (row_base >= n_rows) return;

  const float4* xq = (const float4*)x;   // row stride = 256 float4
  float4* oq = (float4*)out;

#pragma unroll
  for (int t = 0; t < ROWS_PER_WAVE / PAIR; ++t) {
    const int pr = row_base + t * PAIR;

    // ---- 8 independent float4 loads for this pair (TLP hides latency) ----
    float4 xv[PAIR][4];
#pragma unroll
    for (int r = 0; r < PAIR; ++r)
#pragma unroll
      for (int c = 0; c < 4; ++c)
        xv[r][c] = xq[(size_t)(pr + r) * 256 + c * 64 + lane];

    // ---- dot phase: w from LDS (conflict-free b128), xv in regs ----
    float p[PAIR * N_LAYER];
#pragma unroll
    for (int k = 0; k < PAIR * N_LAYER; ++k) p[k] = 0.f;
#pragma unroll
    for (int c = 0; c < 4; ++c) {
      const int col = c * 64 + lane;
#pragma unroll
      for (int i = 0; i < N_LAYER; ++i) {
        const float4 wv = w_lds[i * 256 + col];
#pragma unroll
        for (int r = 0; r < PAIR; ++r) {
          p[r * N_LAYER + i] += xv[r][c].x * wv.x + xv[r][c].y * wv.y +
                                xv[r][c].z * wv.z + xv[r][c].w * wv.w;
        }
      }
    }

    // ---- butterfly: 8 p-values, 6 steps ----
#pragma unroll
    for (int off = 32; off > 0; off >>= 1)
#pragma unroll
      for (int k = 0; k < PAIR * N_LAYER; ++k) p[k] += __shfl_xor(p[k], off, 64);

    // ---- recurrence + store (csum from LDS) ----
#pragma unroll
    for (int r = 0; r < PAIR; ++r) {
      float A = 1.f;
#pragma unroll
      for (int i = 0; i < N_LAYER; ++i)
        A += A * p[r * N_LAYER + i] + e[i];
#pragma unroll
      for (int c = 0; c < 4; ++c) {
        const int col = c * 64 + lane;
        const float4 cs = csum_lds[col];
        float4 o;
        o.x = fmaf(xv[r][c].x, A, cs.x);
        o.y = fmaf(xv[r][c].y, A, cs.y);
        o.z = fmaf(xv[r][c].z, A, cs.z);
        o.w = fmaf(xv[r][c].w, A, cs.w);
        oq[(size_t)(pr + r) * 256 + col] = o;
      }
    }
  }
}

extern "C" void kernel_launch(void* const* d_in, const int* in_sizes, int n_in,
                              void* d_out, int out_size, void* d_ws, size_t ws_size,
                              hipStream_t stream) {
  const float* x = (const float*)d_in[0];
  const float* ww = (const float*)d_in[1];
  const float* wb = (const float*)d_in[2];
  float* out = (float*)d_out;

  const int n_rows = in_sizes[0] / N_FEAT;            // 16384
  const int rows_per_block = 4 * ROWS_PER_WAVE;       // 16
  const int n_blocks = (n_rows + rows_per_block - 1) / rows_per_block;  // 1024
  crossnet_kernel<<<n_blocks, 256, 0, stream>>>(x, ww, wb, out, n_rows);
}

// Round 9
// 122.847 us; speedup vs baseline: 1.6242x; 1.6242x over previous
//
#include <hip/hip_runtime.h>

#define N_FEAT 1024
#define N_LAYER 4
#define RPG 8              // rows per LDS group/tile (32 KB) — one row per wave
#define GPB 4              // groups per block
#define AS1 __attribute__((address_space(1)))
#define AS3 __attribute__((address_space(3)))

// Algebra: xi = A_i*x0 + C_i, C_i = sum_{j<i} b_j (row-independent).
//   p_i = <x0,w_i>, e_i = <C_i,w_i>; A_{i+1} = A_i*(1+p_i) + e_i;
//   out = A_4*x0 + csum.
//
// R4 pipeline (best so far, ~29us kernel) widened to 512-thread blocks:
// 8 waves/block, 1 row per wave per group, 2x32KB LDS dbuf, sync-barrier
// choreography (R4==R5 proved barrier vs counted-vmcnt is irrelevant).
// Occupancy: LDS 64KB/block -> 2 blocks/CU -> 16 waves/CU IF VGPR <= 128.
// Crucially NO __launch_bounds__ min-waves cap: R7/R8 proved the cap makes
// the allocator spill (~100MB+ scratch traffic). Natural live state here is
// ~115 VGPR (w 64 + csum 16 + xv 16 + p/e 8 + addr). If the compiler lands
// >128, occupancy degrades to exactly R4's 8 waves/CU — downside bounded,
// spill risk zero. Validity check: WRITE ~65MB, FETCH <= 70MB.
__global__ __launch_bounds__(512) void crossnet_kernel(
    const float* __restrict__ x,
    const float* __restrict__ weight_w,
    const float* __restrict__ weight_b,
    float* __restrict__ out,
    int n_rows) {
  const int wave = threadIdx.x >> 6;   // 0..7
  const int lane = threadIdx.x & 63;

  __shared__ float buf[2][RPG * N_FEAT];   // 2 x 32 KB

  // ---- hoisted once per kernel: w frags, e, csum (all row-independent) ----
  float4 w[4][N_LAYER];
  float4 csum[4];
  float e[N_LAYER] = {0.f, 0.f, 0.f, 0.f};
#pragma unroll
  for (int c = 0; c < 4; ++c) {
#pragma unroll
    for (int i = 0; i < N_LAYER; ++i)
      w[c][i] = ((const float4*)(weight_w + i * N_FEAT))[c * 64 + lane];
    float4 cum = make_float4(0.f, 0.f, 0.f, 0.f);
#pragma unroll
    for (int i = 0; i < N_LAYER; ++i) {
      if (i > 0)
        e[i] += cum.x * w[c][i].x + cum.y * w[c][i].y +
                cum.z * w[c][i].z + cum.w * w[c][i].w;
      const float4 b = ((const float4*)(weight_b + i * N_FEAT))[c * 64 + lane];
      cum.x += b.x; cum.y += b.y; cum.z += b.z; cum.w += b.w;
    }
    csum[c] = cum;
  }
#pragma unroll
  for (int off = 32; off > 0; off >>= 1)
#pragma unroll
    for (int i = 1; i < N_LAYER; ++i) e[i] += __shfl_xor(e[i], off, 64);

  const int row0 = blockIdx.x * (RPG * GPB);
  if (row0 >= n_rows) return;

  // Wave w stages its own row w of the group (4 x 16B/lane = 4 KB).
  // LDS dest is wave-uniform (HW adds lane*16); global src is per-lane.
  auto stage = [&](int bsel, int grow) {
#pragma unroll
    for (int c = 0; c < 4; ++c) {
      const float* gsrc =
          x + (size_t)(grow + wave) * N_FEAT + (c * 64 + lane) * 4;
      float* ldst = &buf[bsel][wave * N_FEAT + c * 256];
      __builtin_amdgcn_global_load_lds((const AS1 unsigned int*)gsrc,
                                       (AS3 unsigned int*)ldst, 16, 0, 0);
    }
  };

  stage(0, row0);
  __syncthreads();   // vmcnt(0): buf0 ready

#pragma unroll
  for (int t = 0; t < GPB; ++t) {
    const int grow = row0 + t * RPG;

    // issue next group's staging first: stays in flight across compute+store
    if (t + 1 < GPB) stage((t + 1) & 1, grow + RPG);

    const float* B = buf[t & 1];

    // ---- dot phase: read own row from LDS, hold xv in regs ----
    float4 xv[4];
    float p[N_LAYER] = {0.f, 0.f, 0.f, 0.f};
#pragma unroll
    for (int c = 0; c < 4; ++c) {
      xv[c] = *(const float4*)&B[wave * N_FEAT + (c * 64 + lane) * 4];
#pragma unroll
      for (int i = 0; i < N_LAYER; ++i)
        p[i] += xv[c].x * w[c][i].x + xv[c].y * w[c][i].y +
                xv[c].z * w[c][i].z + xv[c].w * w[c][i].w;
    }

    // ---- butterfly: 4 p-values, 6 steps ----
#pragma unroll
    for (int off = 32; off > 0; off >>= 1)
#pragma unroll
      for (int i = 0; i < N_LAYER; ++i) p[i] += __shfl_xor(p[i], off, 64);

    // ---- recurrence + store (xv in regs: x read from HBM exactly once) ----
    float A = 1.f;
#pragma unroll
    for (int i = 0; i < N_LAYER; ++i) A += A * p[i] + e[i];

    const size_t row = grow + wave;
#pragma unroll
    for (int c = 0; c < 4; ++c) {
      float4 o;
      o.x = fmaf(xv[c].x, A, csum[c].x);
      o.y = fmaf(xv[c].y, A, csum[c].y);
      o.z = fmaf(xv[c].z, A, csum[c].z);
      o.w = fmaf(xv[c].w, A, csum[c].w);
      ((float4*)out)[row * 256 + c * 64 + lane] = o;
    }

    __syncthreads();  // drain staging; swap buffers
  }
}

extern "C" void kernel_launch(void* const* d_in, const int* in_sizes, int n_in,
                              void* d_out, int out_size, void* d_ws, size_t ws_size,
                              hipStream_t stream) {
  const float* x = (const float*)d_in[0];
  const float* ww = (const float*)d_in[1];
  const float* wb = (const float*)d_in[2];
  float* out = (float*)d_out;

  const int n_rows = in_sizes[0] / N_FEAT;            // 16384
  const int rows_per_block = RPG * GPB;               // 32
  const int n_blocks = (n_rows + rows_per_block - 1) / rows_per_block;  // 512
  crossnet_kernel<<<n_blocks, 512, 0, stream>>>(x, ww, wb, out, n_rows);
}

// Round 10
// 117.004 us; speedup vs baseline: 1.7053x; 1.0499x over previous
//
#include <hip/hip_runtime.h>

#define N_FEAT 1024
#define N_LAYER 4
#define RPG 4      // rows per group tile (16 KB)
#define NBUF 4     // pipeline depth: 3 groups prefetched ahead
#define GPB 8      // groups per block (32 rows/block)
#define AS1 __attribute__((address_space(1)))
#define AS3 __attribute__((address_space(3)))

// Algebra: xi = A_i*x0 + C_i, C_i = sum_{j<i} b_j (row-independent).
//   p_i = <x0,w_i>, e_i = <C_i,w_i>; A_{i+1} = A_i*(1+p_i) + e_i;
//   out = A_4*x0 + csum.
//
// DEPTH-4 pipeline. The ledger across 10 rounds shows every structure was a
// depth-1 load pipeline (R4 barrier == R5 counted-vmcnt == 29us: the wait
// targets a load issued one short iteration earlier, so time/iter = load
// latency ~8.7K cyc regardless of choreography). Here 3 groups (12 KB/wave,
// 96 KB/CU) are permanently in flight: issue L(t+3), wait ONLY for L(t).
// Same LDS budget as R4 (4 x 16 KB = 64 KB -> 2 blocks/CU, 8 waves/CU),
// same 8 rows/wave amortization (GPB=8), wave-owns-row (R5's proven
// wave-local machinery, no block barriers).
// Exact vmcnt constants (in-order retirement; 4 loads/stage, 4 stores/iter;
// ops the compiler adds can only make waits stricter):
//   newer-than-L(t) at the wait =
//     4*min(3, GPB-1-t) future loads + 4*min(3, t) recent stores
//   t=0:12  t=1:16  t=2:20  t=3..GPB-4:24  GPB-3:20  GPB-2:16  GPB-1:12
// Buffer hazard: L(t+3) overwrites buf[(t-1)&3], consumed at iter t-1;
// leading sched_barrier(0) pins iter t-1's ds_reads before the stage issue.
#define WAITN(n) asm volatile("s_waitcnt vmcnt(" #n ")" ::: "memory")

__global__ __launch_bounds__(256) void crossnet_kernel(
    const float* __restrict__ x,
    const float* __restrict__ weight_w,
    const float* __restrict__ weight_b,
    float* __restrict__ out,
    int n_rows) {
  const int wave = threadIdx.x >> 6;   // 0..3
  const int lane = threadIdx.x & 63;

  __shared__ float buf[NBUF][RPG * N_FEAT];   // 4 x 16 KB

  // ---- hoisted once per kernel: w frags, e, csum (all row-independent) ----
  float4 w[4][N_LAYER];
  float4 csum[4];
  float e[N_LAYER] = {0.f, 0.f, 0.f, 0.f};
#pragma unroll
  for (int c = 0; c < 4; ++c) {
#pragma unroll
    for (int i = 0; i < N_LAYER; ++i)
      w[c][i] = ((const float4*)(weight_w + i * N_FEAT))[c * 64 + lane];
    float4 cum = make_float4(0.f, 0.f, 0.f, 0.f);
#pragma unroll
    for (int i = 0; i < N_LAYER; ++i) {
      if (i > 0)
        e[i] += cum.x * w[c][i].x + cum.y * w[c][i].y +
                cum.z * w[c][i].z + cum.w * w[c][i].w;
      const float4 b = ((const float4*)(weight_b + i * N_FEAT))[c * 64 + lane];
      cum.x += b.x; cum.y += b.y; cum.z += b.z; cum.w += b.w;
    }
    csum[c] = cum;
  }
#pragma unroll
  for (int off = 32; off > 0; off >>= 1)
#pragma unroll
    for (int i = 1; i < N_LAYER; ++i) e[i] += __shfl_xor(e[i], off, 64);

  const int row0 = blockIdx.x * (RPG * GPB);
  if (row0 >= n_rows) return;

  // Wave w stages its own row w of group t (4 x 16B/lane = 4 KB).
  auto stage = [&](int t) {
    const int grow = row0 + t * RPG;
#pragma unroll
    for (int c = 0; c < 4; ++c) {
      const float* gsrc =
          x + (size_t)(grow + wave) * N_FEAT + (c * 64 + lane) * 4;
      float* ldst = &buf[t & (NBUF - 1)][wave * N_FEAT + c * 256];
      __builtin_amdgcn_global_load_lds((const AS1 unsigned int*)gsrc,
                                       (AS3 unsigned int*)ldst, 16, 0, 0);
    }
  };

  // prologue: fill 3 of the 4 buffers
  stage(0);
  stage(1);
  stage(2);

#pragma unroll
  for (int t = 0; t < GPB; ++t) {
    const int grow = row0 + t * RPG;

    __builtin_amdgcn_sched_barrier(0);
    if (t + 3 < GPB) stage(t + 3);

    // wait for L(t) only — 3 groups stay in flight (wave-local, no barrier)
    if (t == 0)            WAITN(12);
    else if (t == 1)       WAITN(16);
    else if (t == 2)       WAITN(20);
    else if (t <= GPB - 4) WAITN(24);
    else if (t == GPB - 3) WAITN(20);
    else if (t == GPB - 2) WAITN(16);
    else                   WAITN(12);
    __builtin_amdgcn_sched_barrier(0);

    const float* B = buf[t & (NBUF - 1)];

    // ---- dot phase: read own row from LDS, hold xv in regs ----
    float4 xv[4];
    float p[N_LAYER] = {0.f, 0.f, 0.f, 0.f};
#pragma unroll
    for (int c = 0; c < 4; ++c) {
      xv[c] = *(const float4*)&B[wave * N_FEAT + (c * 64 + lane) * 4];
#pragma unroll
      for (int i = 0; i < N_LAYER; ++i)
        p[i] += xv[c].x * w[c][i].x + xv[c].y * w[c][i].y +
                xv[c].z * w[c][i].z + xv[c].w * w[c][i].w;
    }

    // ---- butterfly: 4 p-values, 6 steps ----
#pragma unroll
    for (int off = 32; off > 0; off >>= 1)
#pragma unroll
      for (int i = 0; i < N_LAYER; ++i) p[i] += __shfl_xor(p[i], off, 64);

    // ---- recurrence + store (xv in regs: x read from HBM exactly once) ----
    float A = 1.f;
#pragma unroll
    for (int i = 0; i < N_LAYER; ++i) A += A * p[i] + e[i];

    const size_t row = grow + wave;
#pragma unroll
    for (int c = 0; c < 4; ++c) {
      float4 o;
      o.x = fmaf(xv[c].x, A, csum[c].x);
      o.y = fmaf(xv[c].y, A, csum[c].y);
      o.z = fmaf(xv[c].z, A, csum[c].z);
      o.w = fmaf(xv[c].w, A, csum[c].w);
      ((float4*)out)[row * 256 + c * 64 + lane] = o;
    }
  }
}

extern "C" void kernel_launch(void* const* d_in, const int* in_sizes, int n_in,
                              void* d_out, int out_size, void* d_ws, size_t ws_size,
                              hipStream_t stream) {
  const float* x = (const float*)d_in[0];
  const float* ww = (const float*)d_in[1];
  const float* wb = (const float*)d_in[2];
  float* out = (float*)d_out;

  const int n_rows = in_sizes[0] / N_FEAT;            // 16384
  const int rows_per_block = RPG * GPB;               // 32
  const int n_blocks = (n_rows + rows_per_block - 1) / rows_per_block;  // 512
  crossnet_kernel<<<n_blocks, 256, 0, stream>>>(x, ww, wb, out, n_rows);
}